// Round 2
// baseline (303.090 us; speedup 1.0000x reference)
//
#include <hip/hip_runtime.h>

typedef unsigned short u16;

__device__ __forceinline__ float us2f(u16 u){
  unsigned int x = ((unsigned int)u) << 16;
  return __uint_as_float(x);
}
__device__ __forceinline__ u16 f2us(float f){
  unsigned int u = __float_as_uint(f);
  unsigned int r = (u + 0x7fffu + ((u >> 16) & 1u)) >> 16;
  return (u16)r;
}
__device__ __forceinline__ float ldf(const float* p){ return *p; }
__device__ __forceinline__ float ldf(const u16* p){ return us2f(*p); }
__device__ __forceinline__ float4 ld4(const float* p){ return *(const float4*)p; }
__device__ __forceinline__ float4 ld4(const u16* p){
  ushort4 v = *(const ushort4*)p;
  return make_float4(us2f(v.x), us2f(v.y), us2f(v.z), us2f(v.w));
}
__device__ __forceinline__ void st1(float* p, float v){ *p = v; }
__device__ __forceinline__ void st1(u16* p, float v){ *p = f2us(v); }
__device__ __forceinline__ float wredMax(float v){
  #pragma unroll
  for (int o = 32; o > 0; o >>= 1) v = fmaxf(v, __shfl_xor(v, o, 64));
  return v;
}
__device__ __forceinline__ float wredSum(float v){
  #pragma unroll
  for (int o = 32; o > 0; o >>= 1) v += __shfl_xor(v, o, 64);
  return v;
}

#define RT 16   // rows per GEMM block
#define ACAP 128  // adjacency capacity per row

// ---------------- probe: detect input dtype from sector_graph bit pattern ----------------
// fp32 little-endian 0.0f/1.0f => even u16 halves are ALWAYS 0x0000.
// bf16 => even u16 positions hold bf16 elements, ~2% are 0x3F80 (1.0).
__global__ __launch_bounds__(256) void k_probe(const u16* __restrict__ sg, int* __restrict__ flag){
  __shared__ int hit_s;
  const int t = threadIdx.x;
  if (t == 0) hit_s = 0;
  __syncthreads();
  int hit = 0;
  for (int k = t; k < 50000; k += 256)
    if (sg[2 * k] == (u16)0x3F80) hit = 1;
  if (hit) atomicOr(&hit_s, 1);
  __syncthreads();
  if (t == 0) *flag = hit_s;   // 1 = bf16, 0 = fp32
}

// ---------------- K0: CSR adjacency (shared by both GAT layers) ----------------
template<typename T>
__global__ __launch_bounds__(256) void k_adj(const int* __restrict__ flag, int mydt,
    const T* __restrict__ sg, u16* __restrict__ adj, int* __restrict__ cnt)
{
  if (*flag != mydt) return;
  __shared__ int c_s;
  const int t = threadIdx.x;
  const int bi = blockIdx.x;
  const int b = bi / 2000;
  const int i = bi - b * 2000;
  if (t == 0) c_s = 0;
  __syncthreads();
  const T* row = sg + (size_t)bi * 2000;
  for (int j = t; j < 2000; j += 256) {
    if (ldf(&row[j]) > 0.f || j == i) {
      int p = atomicAdd(&c_s, 1);
      if (p < ACAP) adj[(size_t)bi * ACAP + p] = (u16)j;
    }
  }
  __syncthreads();
  if (t == 0) cnt[bi] = min(c_s, ACAP);
}

// ---------------- K1: h = relu(layernorm(x_alpha[:, -1] @ W_in + b_in)) ----------------
template<typename T>
__global__ __launch_bounds__(128) void k_in_ln(const int* __restrict__ flag, int mydt,
    const T* __restrict__ xA, const T* __restrict__ Win,
    const T* __restrict__ bin, const T* __restrict__ lng,
    const T* __restrict__ lnb, float* __restrict__ h)
{
  if (*flag != mydt) return;
  __shared__ float xs[RT][164];     // K=158 padded
  __shared__ float tile[RT][132];
  __shared__ float red1[RT][8], red2[RT][8];
  __shared__ float mu_s[RT], inv_s[RT];
  const int t = threadIdx.x;
  const int blk = blockIdx.x;
  const int row0 = blk * RT;
  const int b = blk / 125;                 // 125 blocks per batch (2000/16)
  const int n0 = (blk % 125) * RT;
  const T* xbase = xA + (((size_t)b * 8 + 7) * 2000 + n0) * 158;

  for (int r = 0; r < RT; r++)
    for (int k = t; k < 164; k += 128)
      xs[r][k] = (k < 158) ? ldf(&xbase[(size_t)r * 158 + k]) : 0.f;
  __syncthreads();

  const int ct = t & 31, rg = t >> 5;
  const int c0 = ct * 4, rb = rg * 4;
  float acc[4][4];
  #pragma unroll
  for (int r = 0; r < 4; r++)
    #pragma unroll
    for (int c = 0; c < 4; c++) acc[r][c] = 0.f;

  for (int k0 = 0; k0 < 160; k0 += 4) {
    float4 a[4];
    #pragma unroll
    for (int r = 0; r < 4; r++) a[r] = *(const float4*)&xs[rb + r][k0];
    #pragma unroll
    for (int kk = 0; kk < 4; kk++) {
      int k = k0 + kk;
      float w[4];
      if (k < 158) {
        float4 wv = ld4(&Win[(size_t)k * 128 + c0]);
        w[0] = wv.x; w[1] = wv.y; w[2] = wv.z; w[3] = wv.w;
      } else { w[0] = w[1] = w[2] = w[3] = 0.f; }
      #pragma unroll
      for (int r = 0; r < 4; r++) {
        float av = kk == 0 ? a[r].x : kk == 1 ? a[r].y : kk == 2 ? a[r].z : a[r].w;
        #pragma unroll
        for (int c = 0; c < 4; c++) acc[r][c] = fmaf(av, w[c], acc[r][c]);
      }
    }
  }

  #pragma unroll
  for (int c = 0; c < 4; c++) {
    float bi_ = ldf(&bin[c0 + c]);
    #pragma unroll
    for (int r = 0; r < 4; r++) tile[rb + r][c0 + c] = acc[r][c] + bi_;
  }
  __syncthreads();

  {
    int rr = t >> 3, q = t & 7;
    float s = 0.f, sq = 0.f;
    #pragma unroll
    for (int c = q * 16; c < q * 16 + 16; c++) { float v = tile[rr][c]; s += v; sq += v * v; }
    red1[rr][q] = s; red2[rr][q] = sq;
  }
  __syncthreads();
  if (t < RT) {
    float s = 0.f, sq = 0.f;
    #pragma unroll
    for (int q = 0; q < 8; q++) { s += red1[t][q]; sq += red2[t][q]; }
    float mu = s * (1.f / 128.f);
    float var = sq * (1.f / 128.f) - mu * mu;
    mu_s[t] = mu; inv_s[t] = rsqrtf(var + 1e-5f);
  }
  __syncthreads();
  float g = ldf(&lng[t]), be = ldf(&lnb[t]);
  for (int r = 0; r < RT; r++) {
    float v = (tile[r][t] - mu_s[r]) * inv_s[r] * g + be;
    h[(size_t)(row0 + r) * 128 + t] = fmaxf(v, 0.f);
  }
}

// ---------------- K2a: x0 = h @ W ; e_src/e_dst per (row, head) ----------------
template<typename T>
__global__ __launch_bounds__(128) void k_gat_pre(const int* __restrict__ flag, int mydt,
    const float* __restrict__ hin, const T* __restrict__ W,
    const T* __restrict__ asrc, const T* __restrict__ adst,
    u16* __restrict__ x0, float* __restrict__ es, float* __restrict__ ed)
{
  if (*flag != mydt) return;
  __shared__ float xs[RT][132];
  __shared__ float tile[RT][132];
  __shared__ float pa[RT][8], pb[RT][8];
  __shared__ float as_s[128], ad_s[128];
  const int t = threadIdx.x;
  const int blk = blockIdx.x;
  const int row0 = blk * RT;

  as_s[t] = ldf(&asrc[t]);
  ad_s[t] = ldf(&adst[t]);
  for (int r = 0; r < RT; r++) xs[r][t] = hin[(size_t)(row0 + r) * 128 + t];
  __syncthreads();

  const int ct = t & 31, rg = t >> 5;
  const int c0 = ct * 4, rb = rg * 4;
  float acc[4][4];
  #pragma unroll
  for (int r = 0; r < 4; r++)
    #pragma unroll
    for (int c = 0; c < 4; c++) acc[r][c] = 0.f;

  for (int k0 = 0; k0 < 128; k0 += 4) {
    float4 a[4];
    #pragma unroll
    for (int r = 0; r < 4; r++) a[r] = *(const float4*)&xs[rb + r][k0];
    #pragma unroll
    for (int kk = 0; kk < 4; kk++) {
      int k = k0 + kk;
      float4 wv = ld4(&W[(size_t)k * 128 + c0]);
      float w[4] = { wv.x, wv.y, wv.z, wv.w };
      #pragma unroll
      for (int r = 0; r < 4; r++) {
        float av = kk == 0 ? a[r].x : kk == 1 ? a[r].y : kk == 2 ? a[r].z : a[r].w;
        #pragma unroll
        for (int c = 0; c < 4; c++) acc[r][c] = fmaf(av, w[c], acc[r][c]);
      }
    }
  }

  #pragma unroll
  for (int r = 0; r < 4; r++)
    #pragma unroll
    for (int c = 0; c < 4; c++) tile[rb + r][c0 + c] = acc[r][c];
  __syncthreads();

  for (int r = 0; r < RT; r++)
    x0[(size_t)(row0 + r) * 128 + t] = f2us(tile[r][t]);

  {
    int rr = t >> 3, q = t & 7;
    float ps = 0.f, pd = 0.f;
    #pragma unroll
    for (int c = q * 16; c < q * 16 + 16; c++) {
      float v = tile[rr][c];
      ps = fmaf(v, as_s[c], ps);
      pd = fmaf(v, ad_s[c], pd);
    }
    pa[rr][q] = ps; pb[rr][q] = pd;
  }
  __syncthreads();
  if (t < 64) {
    int r = t >> 2, hh = t & 3;
    es[(size_t)(row0 + r) * 4 + hh] = pa[r][2 * hh] + pa[r][2 * hh + 1];
    ed[(size_t)(row0 + r) * 4 + hh] = pb[r][2 * hh] + pb[r][2 * hh + 1];
  }
}

// ---------------- K2b: sparse masked-softmax attention + epilogue ----------------
// LAYER 0: h[row] += elu(out + bias0)   (concat heads)
// LAYER 1: h2[row] = mean_h(out) + bias1
template<typename T, int LAYER>
__global__ __launch_bounds__(128) void k_attn(const int* __restrict__ flag, int mydt,
    const u16* __restrict__ adj, const int* __restrict__ cnt,
    const u16* __restrict__ x0,
    const float* __restrict__ es, const float* __restrict__ ed,
    const T* __restrict__ bias, float* __restrict__ hio)
{
  if (*flag != mydt) return;
  __shared__ int idx_s[ACAP];
  __shared__ float sc[4][ACAP];
  __shared__ float red[2][4];
  __shared__ float Msh[4], Ssh[4];
  __shared__ float r128[128];
  const int t = threadIdx.x;
  const int bi = blockIdx.x;        // b*2000 + i
  const int b = bi / 2000;

  const int m = min(cnt[bi], ACAP);  // >=1 (self loop)

  // each thread owns at most one edge (m <= 128)
  int j = 0;
  if (t < m) { j = (int)adj[(size_t)bi * ACAP + t]; idx_s[t] = j; }

  float4 edv = *(const float4*)&ed[(size_t)bi * 4];
  float s0 = -1e30f, s1 = -1e30f, s2 = -1e30f, s3 = -1e30f;
  if (t < m) {
    float4 esv = *(const float4*)&es[((size_t)b * 2000 + j) * 4];
    s0 = edv.x + esv.x; s0 = s0 > 0.f ? s0 : 0.2f * s0;
    s1 = edv.y + esv.y; s1 = s1 > 0.f ? s1 : 0.2f * s1;
    s2 = edv.z + esv.z; s2 = s2 > 0.f ? s2 : 0.2f * s2;
    s3 = edv.w + esv.w; s3 = s3 > 0.f ? s3 : 0.2f * s3;
  }
  float m0 = wredMax(s0), m1 = wredMax(s1), m2 = wredMax(s2), m3 = wredMax(s3);
  if ((t & 63) == 0) { int w = t >> 6; red[w][0] = m0; red[w][1] = m1; red[w][2] = m2; red[w][3] = m3; }
  __syncthreads();
  if (t < 4) Msh[t] = fmaxf(red[0][t], red[1][t]);
  __syncthreads();

  float M0 = Msh[0], M1 = Msh[1], M2 = Msh[2], M3 = Msh[3];
  float p0 = (t < m) ? __expf(s0 - M0) : 0.f;
  float p1 = (t < m) ? __expf(s1 - M1) : 0.f;
  float p2 = (t < m) ? __expf(s2 - M2) : 0.f;
  float p3 = (t < m) ? __expf(s3 - M3) : 0.f;
  sc[0][t] = p0; sc[1][t] = p1; sc[2][t] = p2; sc[3][t] = p3;
  float q0 = wredSum(p0), q1 = wredSum(p1), q2 = wredSum(p2), q3 = wredSum(p3);
  if ((t & 63) == 0) { int w = t >> 6; red[w][0] = q0; red[w][1] = q1; red[w][2] = q2; red[w][3] = q3; }
  __syncthreads();
  if (t < 4) Ssh[t] = red[0][t] + red[1][t];
  __syncthreads();

  // PV gather; thread t owns (head t>>5, chan t&31) == x0 col t
  const int hh = t >> 5;
  float acc = 0.f;
  const u16* x0b = x0 + (size_t)b * 2000 * 128 + t;
  #pragma unroll 4
  for (int e = 0; e < m; e++) {
    int j2 = idx_s[e];
    acc = fmaf(sc[hh][e], us2f(x0b[(size_t)j2 * 128]), acc);
  }
  acc /= Ssh[hh];

  if (LAYER == 0) {
    float v = acc + ldf(&bias[t]);
    v = v > 0.f ? v : (__expf(v) - 1.f);          // elu
    hio[(size_t)bi * 128 + t] += v;               // residual
  } else {
    r128[t] = acc;
    __syncthreads();
    if (t < 32) {
      float v = (r128[t] + r128[t + 32] + r128[t + 64] + r128[t + 96]) * 0.25f + ldf(&bias[t]);
      hio[(size_t)bi * 32 + t] = v;
    }
  }
}

// ---------------- K3: out = h2 @ W_out + b_out ----------------
template<typename T>
__global__ __launch_bounds__(128) void k_out(const int* __restrict__ flag, int mydt,
    const float* __restrict__ h2, const T* __restrict__ Wout,
    const T* __restrict__ bout, T* __restrict__ out)
{
  if (*flag != mydt) return;
  __shared__ float xs[RT][36];
  const int t = threadIdx.x;
  const int blk = blockIdx.x;
  const int row0 = blk * RT;
  for (int idx = t; idx < RT * 32; idx += 128) {
    int r = idx >> 5, k = idx & 31;
    xs[r][k] = h2[(size_t)(row0 + r) * 32 + k];
  }
  __syncthreads();
  const int ct = t & 31, rg = t >> 5;
  const int c0 = ct * 4, rb = rg * 4;
  float acc[4][4];
  #pragma unroll
  for (int r = 0; r < 4; r++)
    #pragma unroll
    for (int c = 0; c < 4; c++) acc[r][c] = 0.f;

  for (int k0 = 0; k0 < 32; k0 += 4) {
    float4 a[4];
    #pragma unroll
    for (int r = 0; r < 4; r++) a[r] = *(const float4*)&xs[rb + r][k0];
    #pragma unroll
    for (int kk = 0; kk < 4; kk++) {
      int k = k0 + kk;
      float4 wv = ld4(&Wout[(size_t)k * 128 + c0]);
      float w[4] = { wv.x, wv.y, wv.z, wv.w };
      #pragma unroll
      for (int r = 0; r < 4; r++) {
        float av = kk == 0 ? a[r].x : kk == 1 ? a[r].y : kk == 2 ? a[r].z : a[r].w;
        #pragma unroll
        for (int c = 0; c < 4; c++) acc[r][c] = fmaf(av, w[c], acc[r][c]);
      }
    }
  }
  float bo[4];
  #pragma unroll
  for (int c = 0; c < 4; c++) bo[c] = ldf(&bout[c0 + c]);
  #pragma unroll
  for (int r = 0; r < 4; r++)
    #pragma unroll
    for (int c = 0; c < 4; c++)
      st1(&out[(size_t)(row0 + rb + r) * 128 + c0 + c], acc[r][c] + bo[c]);
}

extern "C" void kernel_launch(void* const* d_in, const int* in_sizes, int n_in,
                              void* d_out, int out_size, void* d_ws, size_t ws_size,
                              hipStream_t stream) {
  char* ws = (char*)d_ws;
  float* h    = (float*)(ws);                    // 8000*128 f32  = 4,096,000 B
  u16*   x0   = (u16*)  (ws + 4096000);          // 8000*128 bf16 = 2,048,000 B
  float* es   = (float*)(ws + 6144000);          // 8000*4 f32    =   128,000 B
  float* ed   = (float*)(ws + 6272000);          // 8000*4 f32    =   128,000 B
  float* h2   = (float*)(ws + 6400000);          // 8000*32 f32   = 1,024,000 B
  u16*   adj  = (u16*)  (ws + 7424000);          // 8000*128 u16  = 2,048,000 B
  int*   cnt  = (int*)  (ws + 9472000);          // 8000 i32      =    32,000 B
  int*   flag = (int*)  (ws + 9504000);          // 4 B

  // probe dtype (writes flag: 0=fp32, 1=bf16)
  k_probe<<<1, 256, 0, stream>>>((const u16*)d_in[1], flag);

  // Launch BOTH dtype variants of every stage; each early-exits unless flag matches.
  #define FOR_BOTH(CALL_F, CALL_B) do { CALL_F; CALL_B; } while(0)

  FOR_BOTH(
    (k_adj<float><<<8000, 256, 0, stream>>>(flag, 0, (const float*)d_in[1], adj, cnt)),
    (k_adj<u16  ><<<8000, 256, 0, stream>>>(flag, 1, (const u16*  )d_in[1], adj, cnt)));

  FOR_BOTH(
    (k_in_ln<float><<<500, 128, 0, stream>>>(flag, 0, (const float*)d_in[0], (const float*)d_in[2],
        (const float*)d_in[3], (const float*)d_in[4], (const float*)d_in[5], h)),
    (k_in_ln<u16  ><<<500, 128, 0, stream>>>(flag, 1, (const u16*  )d_in[0], (const u16*  )d_in[2],
        (const u16*  )d_in[3], (const u16*  )d_in[4], (const u16*  )d_in[5], h)));

  FOR_BOTH(
    (k_gat_pre<float><<<500, 128, 0, stream>>>(flag, 0, h, (const float*)d_in[6],
        (const float*)d_in[7], (const float*)d_in[8], x0, es, ed)),
    (k_gat_pre<u16  ><<<500, 128, 0, stream>>>(flag, 1, h, (const u16*  )d_in[6],
        (const u16*  )d_in[7], (const u16*  )d_in[8], x0, es, ed)));

  FOR_BOTH(
    (k_attn<float,0><<<8000, 128, 0, stream>>>(flag, 0, adj, cnt, x0, es, ed, (const float*)d_in[9], h)),
    (k_attn<u16  ,0><<<8000, 128, 0, stream>>>(flag, 1, adj, cnt, x0, es, ed, (const u16*  )d_in[9], h)));

  FOR_BOTH(
    (k_gat_pre<float><<<500, 128, 0, stream>>>(flag, 0, h, (const float*)d_in[10],
        (const float*)d_in[11], (const float*)d_in[12], x0, es, ed)),
    (k_gat_pre<u16  ><<<500, 128, 0, stream>>>(flag, 1, h, (const u16*  )d_in[10],
        (const u16*  )d_in[11], (const u16*  )d_in[12], x0, es, ed)));

  FOR_BOTH(
    (k_attn<float,1><<<8000, 128, 0, stream>>>(flag, 0, adj, cnt, x0, es, ed, (const float*)d_in[13], h2)),
    (k_attn<u16  ,1><<<8000, 128, 0, stream>>>(flag, 1, adj, cnt, x0, es, ed, (const u16*  )d_in[13], h2)));

  FOR_BOTH(
    (k_out<float><<<500, 128, 0, stream>>>(flag, 0, h2, (const float*)d_in[14],
        (const float*)d_in[15], (float*)d_out)),
    (k_out<u16  ><<<500, 128, 0, stream>>>(flag, 1, h2, (const u16*  )d_in[14],
        (const u16*  )d_in[15], (u16*)d_out)));
}

// Round 3
// 247.818 us; speedup vs baseline: 1.2230x; 1.2230x over previous
//
#include <hip/hip_runtime.h>

typedef unsigned short u16;

__device__ __forceinline__ float us2f(u16 u){
  unsigned int x = ((unsigned int)u) << 16;
  return __uint_as_float(x);
}
__device__ __forceinline__ u16 f2us(float f){
  unsigned int u = __float_as_uint(f);
  unsigned int r = (u + 0x7fffu + ((u >> 16) & 1u)) >> 16;
  return (u16)r;
}
__device__ __forceinline__ float ldf(const float* p){ return *p; }
__device__ __forceinline__ float ldf(const u16* p){ return us2f(*p); }
__device__ __forceinline__ float4 ld4(const float* p){ return *(const float4*)p; }
__device__ __forceinline__ float4 ld4(const u16* p){
  ushort4 v = *(const ushort4*)p;
  return make_float4(us2f(v.x), us2f(v.y), us2f(v.z), us2f(v.w));
}
__device__ __forceinline__ float wredMax(float v){
  #pragma unroll
  for (int o = 32; o > 0; o >>= 1) v = fmaxf(v, __shfl_xor(v, o, 64));
  return v;
}
__device__ __forceinline__ float wredSum(float v){
  #pragma unroll
  for (int o = 32; o > 0; o >>= 1) v += __shfl_xor(v, o, 64);
  return v;
}

#define RT 16     // rows per GEMM block
#define ACAP 128  // adjacency capacity per row

// 4x4-per-thread register-tile GEMM inner loop. xs: [16][LDA] fp32 LDS tile.
// W: row-major [KREAL][128], dtype T. acc += xs[rb..rb+3][:] * W[:][c0..c0+3].
template<typename T, int KMAX, int KREAL, int LDA>
__device__ __forceinline__ void gemm4x4(const float* xs, const T* __restrict__ W,
                                        int rb, int c0, float acc[4][4]){
  for (int k0 = 0; k0 < KMAX; k0 += 4){
    float4 a[4];
    #pragma unroll
    for (int r = 0; r < 4; r++) a[r] = *(const float4*)(xs + (size_t)(rb + r) * LDA + k0);
    #pragma unroll
    for (int kk = 0; kk < 4; kk++){
      int k = k0 + kk;
      float w0 = 0.f, w1 = 0.f, w2 = 0.f, w3 = 0.f;
      if (KREAL == KMAX || k < KREAL){
        float4 wv = ld4(&W[(size_t)k * 128 + c0]);
        w0 = wv.x; w1 = wv.y; w2 = wv.z; w3 = wv.w;
      }
      #pragma unroll
      for (int r = 0; r < 4; r++){
        float av = ((const float*)&a[r])[kk];
        acc[r][0] = fmaf(av, w0, acc[r][0]);
        acc[r][1] = fmaf(av, w1, acc[r][1]);
        acc[r][2] = fmaf(av, w2, acc[r][2]);
        acc[r][3] = fmaf(av, w3, acc[r][3]);
      }
    }
  }
}

// ---------------- flag init ----------------
__global__ __launch_bounds__(64) void k_init(int* __restrict__ flag){
  if (threadIdx.x == 0) *flag = 0;
}

// ---------------- probe: detect input dtype from sector_graph bit pattern ----------------
// fp32 little-endian 0.0f/1.0f => even u16 halves are ALWAYS 0x0000.
// bf16 => even u16 positions hold bf16 elements, ~2% are 0x3F80 (1.0).
__global__ __launch_bounds__(256) void k_probe(const u16* __restrict__ sg, int* __restrict__ flag){
  int idx = blockIdx.x * 256 + threadIdx.x;       // 65536 threads
  bool hit = (sg[2 * (size_t)idx] == (u16)0x3F80) ||
             (sg[2 * (size_t)(idx + 65536)] == (u16)0x3F80);
  if (__any(hit) && (threadIdx.x & 63) == 0) atomicOr(flag, 1);
}

// ---------------- K0: CSR adjacency (shared by both GAT layers) ----------------
__global__ __launch_bounds__(256) void k_adj(const int* __restrict__ flag,
    const void* __restrict__ sgv, u16* __restrict__ adj, int* __restrict__ cnt)
{
  const int isbf = *flag;
  __shared__ int c_s;
  const int t = threadIdx.x;
  const int bi = blockIdx.x;
  const int b = bi / 2000;
  const int i = bi - b * 2000;
  if (t == 0) c_s = 0;
  __syncthreads();
  if (isbf){
    const u16* row = (const u16*)sgv + (size_t)bi * 2000;
    for (int j = t; j < 2000; j += 256)
      if (us2f(row[j]) > 0.f || j == i){
        int p = atomicAdd(&c_s, 1);
        if (p < ACAP) adj[(size_t)bi * ACAP + p] = (u16)j;
      }
  } else {
    const float* row = (const float*)sgv + (size_t)bi * 2000;
    for (int j = t; j < 2000; j += 256)
      if (row[j] > 0.f || j == i){
        int p = atomicAdd(&c_s, 1);
        if (p < ACAP) adj[(size_t)bi * ACAP + p] = (u16)j;
      }
  }
  __syncthreads();
  if (t == 0) cnt[bi] = min(c_s, ACAP);
}

// ---------------- K1: fused  h = relu(LN(x@W_in+b_in));  x0=h@W0;  es/ed ----------------
__global__ __launch_bounds__(128) void k_inln_gat0(const int* __restrict__ flag,
    const void* __restrict__ xAv, const void* __restrict__ Winv,
    const void* __restrict__ binv, const void* __restrict__ lngv,
    const void* __restrict__ lnbv, const void* __restrict__ W0v,
    const void* __restrict__ as0v, const void* __restrict__ ad0v,
    float* __restrict__ h, u16* __restrict__ x0,
    float* __restrict__ es, float* __restrict__ ed)
{
  const int isbf = *flag;
  __shared__ float xs[RT][164];     // K=158 padded; reused as GEMM2 out tile
  __shared__ float tile[RT][132];   // GEMM1 out / h tile
  __shared__ float red1[RT][8], red2[RT][8];
  __shared__ float mu_s[RT], inv_s[RT];
  __shared__ float pa[RT][8], pb[RT][8];
  __shared__ float as_s[128], ad_s[128];
  const int t = threadIdx.x;
  const int blk = blockIdx.x;
  const int row0 = blk * RT;
  const int b = blk / 125;                 // 125 blocks per batch (2000/16)
  const int n0 = (blk % 125) * RT;
  const size_t xoff = (((size_t)b * 8 + 7) * 2000 + n0) * 158;

  as_s[t] = isbf ? us2f(((const u16*)as0v)[t]) : ((const float*)as0v)[t];
  ad_s[t] = isbf ? us2f(((const u16*)ad0v)[t]) : ((const float*)ad0v)[t];

  if (isbf){
    const u16* xb = (const u16*)xAv + xoff;
    for (int r = 0; r < RT; r++)
      for (int k = t; k < 164; k += 128)
        xs[r][k] = (k < 158) ? us2f(xb[(size_t)r * 158 + k]) : 0.f;
  } else {
    const float* xb = (const float*)xAv + xoff;
    for (int r = 0; r < RT; r++)
      for (int k = t; k < 164; k += 128)
        xs[r][k] = (k < 158) ? xb[(size_t)r * 158 + k] : 0.f;
  }
  __syncthreads();

  const int ct = t & 31, rg = t >> 5;
  const int c0 = ct * 4, rb = rg * 4;
  float acc[4][4];
  #pragma unroll
  for (int r = 0; r < 4; r++)
    #pragma unroll
    for (int c = 0; c < 4; c++) acc[r][c] = 0.f;

  if (isbf) gemm4x4<u16,  160, 158, 164>(&xs[0][0], (const u16*)Winv,   rb, c0, acc);
  else      gemm4x4<float,160, 158, 164>(&xs[0][0], (const float*)Winv, rb, c0, acc);

  #pragma unroll
  for (int c = 0; c < 4; c++){
    float bi_ = isbf ? us2f(((const u16*)binv)[c0 + c]) : ((const float*)binv)[c0 + c];
    #pragma unroll
    for (int r = 0; r < 4; r++) tile[rb + r][c0 + c] = acc[r][c] + bi_;
  }
  __syncthreads();

  // layernorm stats: 8 threads per row
  {
    int rr = t >> 3, q = t & 7;
    float s = 0.f, sq = 0.f;
    #pragma unroll
    for (int c = q * 16; c < q * 16 + 16; c++){ float v = tile[rr][c]; s += v; sq += v * v; }
    red1[rr][q] = s; red2[rr][q] = sq;
  }
  __syncthreads();
  if (t < RT){
    float s = 0.f, sq = 0.f;
    #pragma unroll
    for (int q = 0; q < 8; q++){ s += red1[t][q]; sq += red2[t][q]; }
    float mu = s * (1.f / 128.f);
    float var = sq * (1.f / 128.f) - mu * mu;
    mu_s[t] = mu; inv_s[t] = rsqrtf(var + 1e-5f);
  }
  __syncthreads();
  {
    float g  = isbf ? us2f(((const u16*)lngv)[t]) : ((const float*)lngv)[t];
    float be = isbf ? us2f(((const u16*)lnbv)[t]) : ((const float*)lnbv)[t];
    for (int r = 0; r < RT; r++){
      float v = (tile[r][t] - mu_s[r]) * inv_s[r] * g + be;
      v = fmaxf(v, 0.f);
      tile[r][t] = v;                              // h tile stays in LDS
      h[(size_t)(row0 + r) * 128 + t] = v;         // needed by attn0 residual + layer1
    }
  }
  __syncthreads();

  // GEMM2: x0tile = htile @ W0
  #pragma unroll
  for (int r = 0; r < 4; r++)
    #pragma unroll
    for (int c = 0; c < 4; c++) acc[r][c] = 0.f;
  if (isbf) gemm4x4<u16,  128, 128, 132>(&tile[0][0], (const u16*)W0v,   rb, c0, acc);
  else      gemm4x4<float,128, 128, 132>(&tile[0][0], (const float*)W0v, rb, c0, acc);
  #pragma unroll
  for (int r = 0; r < 4; r++)
    #pragma unroll
    for (int c = 0; c < 4; c++) xs[rb + r][c0 + c] = acc[r][c];
  __syncthreads();

  for (int r = 0; r < RT; r++)
    x0[(size_t)(row0 + r) * 128 + t] = f2us(xs[r][t]);

  {
    int rr = t >> 3, q = t & 7;
    float ps = 0.f, pd = 0.f;
    #pragma unroll
    for (int c = q * 16; c < q * 16 + 16; c++){
      float v = xs[rr][c];
      ps = fmaf(v, as_s[c], ps);
      pd = fmaf(v, ad_s[c], pd);
    }
    pa[rr][q] = ps; pb[rr][q] = pd;
  }
  __syncthreads();
  if (t < 64){
    int r = t >> 2, hh = t & 3;
    es[(size_t)(row0 + r) * 4 + hh] = pa[r][2 * hh] + pa[r][2 * hh + 1];
    ed[(size_t)(row0 + r) * 4 + hh] = pb[r][2 * hh] + pb[r][2 * hh + 1];
  }
}

// ---------------- K2: layer-1 projection  x1 = h @ W1 ; es/ed ----------------
__global__ __launch_bounds__(128) void k_gat_pre(const int* __restrict__ flag,
    const float* __restrict__ hin, const void* __restrict__ Wv,
    const void* __restrict__ asv, const void* __restrict__ adv,
    u16* __restrict__ x0, float* __restrict__ es, float* __restrict__ ed)
{
  const int isbf = *flag;
  __shared__ float xs[RT][132];
  __shared__ float tile[RT][132];
  __shared__ float pa[RT][8], pb[RT][8];
  __shared__ float as_s[128], ad_s[128];
  const int t = threadIdx.x;
  const int blk = blockIdx.x;
  const int row0 = blk * RT;

  as_s[t] = isbf ? us2f(((const u16*)asv)[t]) : ((const float*)asv)[t];
  ad_s[t] = isbf ? us2f(((const u16*)adv)[t]) : ((const float*)adv)[t];
  for (int r = 0; r < RT; r++) xs[r][t] = hin[(size_t)(row0 + r) * 128 + t];
  __syncthreads();

  const int ct = t & 31, rg = t >> 5;
  const int c0 = ct * 4, rb = rg * 4;
  float acc[4][4];
  #pragma unroll
  for (int r = 0; r < 4; r++)
    #pragma unroll
    for (int c = 0; c < 4; c++) acc[r][c] = 0.f;

  if (isbf) gemm4x4<u16,  128, 128, 132>(&xs[0][0], (const u16*)Wv,   rb, c0, acc);
  else      gemm4x4<float,128, 128, 132>(&xs[0][0], (const float*)Wv, rb, c0, acc);

  #pragma unroll
  for (int r = 0; r < 4; r++)
    #pragma unroll
    for (int c = 0; c < 4; c++) tile[rb + r][c0 + c] = acc[r][c];
  __syncthreads();

  for (int r = 0; r < RT; r++)
    x0[(size_t)(row0 + r) * 128 + t] = f2us(tile[r][t]);

  {
    int rr = t >> 3, q = t & 7;
    float ps = 0.f, pd = 0.f;
    #pragma unroll
    for (int c = q * 16; c < q * 16 + 16; c++){
      float v = tile[rr][c];
      ps = fmaf(v, as_s[c], ps);
      pd = fmaf(v, ad_s[c], pd);
    }
    pa[rr][q] = ps; pb[rr][q] = pd;
  }
  __syncthreads();
  if (t < 64){
    int r = t >> 2, hh = t & 3;
    es[(size_t)(row0 + r) * 4 + hh] = pa[r][2 * hh] + pa[r][2 * hh + 1];
    ed[(size_t)(row0 + r) * 4 + hh] = pb[r][2 * hh] + pb[r][2 * hh + 1];
  }
}

// ---------------- K3: sparse masked-softmax attention ----------------
// LAYER 0: h[row] += elu(out + bias0)             (concat heads)
// LAYER 1: fused output: out = (mean_h + bias1) @ W_out + b_out  (dtype store)
template<int LAYER>
__global__ __launch_bounds__(128) void k_attn(const int* __restrict__ flag,
    const u16* __restrict__ adj, const int* __restrict__ cnt,
    const u16* __restrict__ x0,
    const float* __restrict__ es, const float* __restrict__ ed,
    const void* __restrict__ biasv, float* __restrict__ hio,
    const void* __restrict__ Woutv, const void* __restrict__ boutv,
    void* __restrict__ outv)
{
  const int isbf = *flag;
  __shared__ int idx_s[ACAP];
  __shared__ float sc[4][ACAP];
  __shared__ float red[2][4];
  __shared__ float Msh[4], Ssh[4];
  __shared__ float r128[128];
  __shared__ float mrow[32];
  const int t = threadIdx.x;
  const int bi = blockIdx.x;        // b*2000 + i
  const int b = bi / 2000;

  const int m = min(cnt[bi], ACAP);  // >=1 (self loop)

  int j = 0;
  if (t < m){ j = (int)adj[(size_t)bi * ACAP + t]; idx_s[t] = j; }

  float4 edv = *(const float4*)&ed[(size_t)bi * 4];
  float s0 = -1e30f, s1 = -1e30f, s2 = -1e30f, s3 = -1e30f;
  if (t < m){
    float4 esv = *(const float4*)&es[((size_t)b * 2000 + j) * 4];
    s0 = edv.x + esv.x; s0 = s0 > 0.f ? s0 : 0.2f * s0;
    s1 = edv.y + esv.y; s1 = s1 > 0.f ? s1 : 0.2f * s1;
    s2 = edv.z + esv.z; s2 = s2 > 0.f ? s2 : 0.2f * s2;
    s3 = edv.w + esv.w; s3 = s3 > 0.f ? s3 : 0.2f * s3;
  }
  float m0 = wredMax(s0), m1 = wredMax(s1), m2 = wredMax(s2), m3 = wredMax(s3);
  if ((t & 63) == 0){ int w = t >> 6; red[w][0] = m0; red[w][1] = m1; red[w][2] = m2; red[w][3] = m3; }
  __syncthreads();
  if (t < 4) Msh[t] = fmaxf(red[0][t], red[1][t]);
  __syncthreads();

  float M0 = Msh[0], M1 = Msh[1], M2 = Msh[2], M3 = Msh[3];
  float p0 = (t < m) ? __expf(s0 - M0) : 0.f;
  float p1 = (t < m) ? __expf(s1 - M1) : 0.f;
  float p2 = (t < m) ? __expf(s2 - M2) : 0.f;
  float p3 = (t < m) ? __expf(s3 - M3) : 0.f;
  if (t < ACAP){ sc[0][t] = p0; sc[1][t] = p1; sc[2][t] = p2; sc[3][t] = p3; }
  float q0 = wredSum(p0), q1 = wredSum(p1), q2 = wredSum(p2), q3 = wredSum(p3);
  if ((t & 63) == 0){ int w = t >> 6; red[w][0] = q0; red[w][1] = q1; red[w][2] = q2; red[w][3] = q3; }
  __syncthreads();
  if (t < 4) Ssh[t] = red[0][t] + red[1][t];
  __syncthreads();

  // PV gather; thread t owns (head t>>5, chan t&31) == x0 col t
  const int hh = t >> 5;
  float acc = 0.f;
  const u16* x0b = x0 + (size_t)b * 2000 * 128 + t;
  #pragma unroll 4
  for (int e = 0; e < m; e++){
    int j2 = idx_s[e];
    acc = fmaf(sc[hh][e], us2f(x0b[(size_t)j2 * 128]), acc);
  }
  acc /= Ssh[hh];

  if (LAYER == 0){
    float bi_ = isbf ? us2f(((const u16*)biasv)[t]) : ((const float*)biasv)[t];
    float v = acc + bi_;
    v = v > 0.f ? v : (__expf(v) - 1.f);          // elu
    hio[(size_t)bi * 128 + t] += v;               // residual
  } else {
    r128[t] = acc;
    __syncthreads();
    if (t < 32){
      float bi_ = isbf ? us2f(((const u16*)biasv)[t]) : ((const float*)biasv)[t];
      mrow[t] = (r128[t] + r128[t + 32] + r128[t + 64] + r128[t + 96]) * 0.25f + bi_;
    }
    __syncthreads();
    // out[bi][t] = mrow @ W_out[:,t] + b_out[t]
    float o;
    if (isbf){
      const u16* Wo = (const u16*)Woutv;
      o = us2f(((const u16*)boutv)[t]);
      #pragma unroll
      for (int k = 0; k < 32; k++) o = fmaf(mrow[k], us2f(Wo[(size_t)k * 128 + t]), o);
      ((u16*)outv)[(size_t)bi * 128 + t] = f2us(o);
    } else {
      const float* Wo = (const float*)Woutv;
      o = ((const float*)boutv)[t];
      #pragma unroll
      for (int k = 0; k < 32; k++) o = fmaf(mrow[k], Wo[(size_t)k * 128 + t], o);
      ((float*)outv)[(size_t)bi * 128 + t] = o;
    }
  }
}

extern "C" void kernel_launch(void* const* d_in, const int* in_sizes, int n_in,
                              void* d_out, int out_size, void* d_ws, size_t ws_size,
                              hipStream_t stream) {
  char* ws = (char*)d_ws;
  float* h    = (float*)(ws);                    // 8000*128 f32  = 4,096,000 B
  u16*   x0   = (u16*)  (ws + 4096000);          // 8000*128 bf16 = 2,048,000 B
  float* es   = (float*)(ws + 6144000);          // 8000*4 f32    =   128,000 B
  float* ed   = (float*)(ws + 6272000);          // 8000*4 f32    =   128,000 B
  u16*   adj  = (u16*)  (ws + 6400000);          // 8000*128 u16  = 2,048,000 B
  int*   cnt  = (int*)  (ws + 8448000);          // 8000 i32      =    32,000 B
  int*   flag = (int*)  (ws + 8480000);          // 4 B

  k_init <<<1, 64, 0, stream>>>(flag);
  k_probe<<<256, 256, 0, stream>>>((const u16*)d_in[1], flag);
  k_adj  <<<8000, 256, 0, stream>>>(flag, d_in[1], adj, cnt);
  k_inln_gat0<<<500, 128, 0, stream>>>(flag, d_in[0], d_in[2], d_in[3], d_in[4], d_in[5],
                                       d_in[6], d_in[7], d_in[8], h, x0, es, ed);
  k_attn<0><<<8000, 128, 0, stream>>>(flag, adj, cnt, x0, es, ed, d_in[9], h,
                                      nullptr, nullptr, nullptr);
  k_gat_pre<<<500, 128, 0, stream>>>(flag, h, d_in[10], d_in[11], d_in[12], x0, es, ed);
  k_attn<1><<<8000, 128, 0, stream>>>(flag, adj, cnt, x0, es, ed, d_in[13], nullptr,
                                      d_in[14], d_in[15], d_out);
}